// Round 1
// baseline (1591.842 us; speedup 1.0000x reference)
//
#include <hip/hip_runtime.h>
#include <hip/hip_bf16.h>
#include <stdint.h>

// SimpleRNN: B=64, S=512, H=1024, V=128
// Phase 1 (R15): batch-split persistent recurrence.
//   64 wgs = 2 batch-halves x 32 col-groups. Each wg: 32 rows x 32 cols of h,
//   8 waves = 8-way K-split (128 k each, distinct slices -> per-CU h pull
//   halves to 64 KB/step vs R14's 128 KB; theory: per-CU L3 return-BW bound
//   at ~32 B/cyc).
//   Per-WAVE flags (512): each wave drains its own h store (vmcnt(0), per-wave
//   counter) and publishes immediately -- wg barrier moved off the publish
//   path. Consumers wait the union: 4 producer wgs x 8 waves = 32 flags,
//   one per lane. Triple-buffered h in MFMA A-frag layout, sc1 L3 exchange,
//   descending-vmcnt load pipeline (R13-proven form, 8 loads/wave now).
// Phase 2: logits GEMM (hidden bf16 @ W_out bf16, 32x32x16 MFMA) + b_out
//   (unchanged; g_hidden layout identical: bh plays R14's mi role).

#define Bz 64
#define Sz 512
#define Hz 1024
#define Vz 128
#define NWG 64    // 2 batch-halves x 32 col-groups
#define COLS 32   // columns of W_hh per workgroup
#define WGT 512   // 8 waves = 8-way K-split (128 k each)

typedef __attribute__((ext_vector_type(8)))  short short8;
typedef __attribute__((ext_vector_type(16))) float f32x16;
typedef __attribute__((ext_vector_type(4)))  unsigned u32x4;   // asm-friendly 16B

// h TRIPLE buffer in MFMA A-fragment order:
// g_hfrag[gen][bh][kb=k>>4][lane=((k>>3)&1)*32+r][j=k&7], r = row within half
__device__ __align__(16) unsigned short g_hfrag[3][2][64][64][8];   // 3 x 128 KB
// hidden states, fragment order per step: [s][bh][kb][lane][8]  (64 MB)
__device__ __align__(16) unsigned short g_hidden[(size_t)Sz*2*64*64*8];
// W_out packed for 32x32x16 B-frags: [kb][nt][lane][8]  (256 KB)
__device__ __align__(16) unsigned short g_wout[64*4*64*8];

__device__ __forceinline__ unsigned short f2bf(float f) {
  union { float f; unsigned u; } v; v.f = f;
  unsigned r = v.u + 0x7FFFu + ((v.u >> 16) & 1u);      // RNE
  return (unsigned short)(r >> 16);
}

__device__ __forceinline__ float fast_tanh(float x) {
  float cx = fminf(9.0f, fmaxf(-9.0f, x));
  float e  = __builtin_amdgcn_exp2f(cx * 2.88539008178f);   // e^(2x)
  return (e - 1.0f) * __builtin_amdgcn_rcpf(e + 1.0f);
}

// 8 coherent (sc1 -> L3) 16-B loads, NO drain — pipeline issue stage.
// Each instruction is a fully-coalesced 1 KB wave read (lane stride 16 B).
__device__ __forceinline__ void load8_nodrain(const unsigned short* p0, u32x4 t[8]) {
  const unsigned short* p1 = p0 + 2048;   // +4096 B (4 planes)
  asm volatile(
    "global_load_dwordx4 %0, %8, off sc1\n\t"
    "global_load_dwordx4 %1, %8, off offset:1024 sc1\n\t"
    "global_load_dwordx4 %2, %8, off offset:2048 sc1\n\t"
    "global_load_dwordx4 %3, %8, off offset:3072 sc1\n\t"
    "global_load_dwordx4 %4, %9, off sc1\n\t"
    "global_load_dwordx4 %5, %9, off offset:1024 sc1\n\t"
    "global_load_dwordx4 %6, %9, off offset:2048 sc1\n\t"
    "global_load_dwordx4 %7, %9, off offset:3072 sc1"
    : "=&v"(t[0]), "=&v"(t[1]), "=&v"(t[2]), "=&v"(t[3]),
      "=&v"(t[4]), "=&v"(t[5]), "=&v"(t[6]), "=&v"(t[7])
    : "v"(p0), "v"(p1)
    : "memory");
}

// agent-scope write-through stores (visible at L3 once vmcnt retires)
__device__ __forceinline__ void store16_sc1(unsigned short* p, u32x4 v) {
  asm volatile("global_store_dwordx4 %0, %1, off sc1" :: "v"(p), "v"(v) : "memory");
}
__device__ __forceinline__ void store4_sc1(unsigned short* p, unsigned v) {
  asm volatile("global_store_dword %0, %1, off sc1" :: "v"(p), "v"(v) : "memory");
}

// ---- Phase 0: pack W_out (H,V) fp32 -> [kb][nt][lane][8] bf16 (32x32 B-frag) --
__global__ void pack_wout(const float* __restrict__ W_out) {
  int gid = blockIdx.x * blockDim.x + threadIdx.x;      // 0..16383
  int lane = gid & 63;
  int nt   = (gid >> 6) & 3;
  int kb   = gid >> 8;
  int n = nt * 32 + (lane & 31);
  int k0 = kb * 16 + (lane >> 5) * 8;
  unsigned short t[8];
#pragma unroll
  for (int j = 0; j < 8; ++j)
    t[j] = f2bf(W_out[(size_t)(k0 + j) * Vz + n]);
  uint4 w;
  w.x = (unsigned)t[0] | ((unsigned)t[1] << 16);
  w.y = (unsigned)t[2] | ((unsigned)t[3] << 16);
  w.z = (unsigned)t[4] | ((unsigned)t[5] << 16);
  w.w = (unsigned)t[6] | ((unsigned)t[7] << 16);
  *(uint4*)&g_wout[(size_t)gid * 8] = w;
}

// ---------------- Phase 1: persistent recurrence -----------------------------
__global__ __launch_bounds__(WGT) void rnn_persistent(
    const int* __restrict__ x, const float* __restrict__ h0,
    const float* __restrict__ W_xh, const float* __restrict__ W_hh,
    const float* __restrict__ b_h, float* __restrict__ out,
    unsigned* __restrict__ flags)
{
  // W slice (32 cols): [kb(64)][lane=kq*32+n][8] -> B-frag via ds_read_b128
  __shared__ unsigned short ldsW[64 * 64 * 8];          // 64 KB
  // 8 K-split partial regions, XOR-swizzled: red[ki*1024 + m*32 + (c^m)]
  __shared__ float red[8 * 1024];                       // 32 KB
  // 96 KB total -> 1 wg per CU (forces spreading of all 64 wgs)

  const int g    = blockIdx.x;        // 0..63
  const int bh   = g >> 5;            // batch half (rows bh*32 .. +32)
  const int cg   = g & 31;            // col-group
  const int n0g  = cg * COLS;         // global column base of W slice
  const int tid  = threadIdx.x;
  const int lane = tid & 63;
  const int ki   = tid >> 6;          // wave = K-split 0..7 (128 k each)
  const int bn   = lane & 31;

  // ---- stage W_hh[:, n0g : n0g+32) -> ldsW (one-time) ----
  for (int idx = tid; idx < 64 * 64; idx += WGT) {
    int kb = idx >> 6, L = idx & 63;
    int n = L & 31, kq = L >> 5;
    unsigned short t[8];
#pragma unroll
    for (int j = 0; j < 8; ++j)
      t[j] = f2bf(W_hh[(size_t)(kb * 16 + kq * 8 + j) * Hz + n0g + n]);
    uint4 w;
    w.x = (unsigned)t[0] | ((unsigned)t[1] << 16);
    w.y = (unsigned)t[2] | ((unsigned)t[3] << 16);
    w.z = (unsigned)t[4] | ((unsigned)t[5] << 16);
    w.w = (unsigned)t[6] | ((unsigned)t[7] << 16);
    *(uint4*)&ldsW[(size_t)idx * 8] = w;
  }

  // ---- h0 -> g_hfrag[0]; wg g stages lines [g*128, g*128+128) of 8192 ----
  if (tid < 128) {
    int s_idx = g * 128 + tid;
    int fbh = s_idx >> 12, fkb = (s_idx >> 6) & 63, fL = s_idx & 63;
    int m = fbh * 32 + (fL & 31);
    int k = fkb * 16 + (fL >> 5) * 8;
    const float* src = &h0[(size_t)m * Hz + k];
    float4 a0 = *(const float4*)&src[0];
    float4 a1 = *(const float4*)&src[4];
    u32x4 w;
    w.x = (unsigned)f2bf(a0.x) | ((unsigned)f2bf(a0.y) << 16);
    w.y = (unsigned)f2bf(a0.z) | ((unsigned)f2bf(a0.w) << 16);
    w.z = (unsigned)f2bf(a1.x) | ((unsigned)f2bf(a1.y) << 16);
    w.w = (unsigned)f2bf(a1.z) | ((unsigned)f2bf(a1.w) << 16);
    store16_sc1(&g_hfrag[0][fbh][fkb][fL][0], w);
  }

  // ---- init: LDS ready for all waves; each wave certifies its OWN stores ----
  __syncthreads();                                  // ldsW visible to all waves
  asm volatile("s_waitcnt vmcnt(0)" ::: "memory");  // per-wave h0-store drain
  if (lane == 0)
    __hip_atomic_store(&flags[(g * 8 + ki) * 4], 1u, __ATOMIC_RELAXED,
                       __HIP_MEMORY_SCOPE_AGENT);

  // epilogue mapping: 512 threads -> 32 rows x 16 col-pairs
  const int er   = tid & 31;                  // row within batch half
  const int em   = bh * 32 + er;              // global batch row
  const int c0   = (tid >> 5) * 2;            // col within wg slice (even)
  const int kcol = n0g + c0;                  // global h column
  const int kb_g = kcol >> 4;
  const int kq2  = (kcol >> 3) & 1;
  const int lslot = kq2 * 32 + er;
  const size_t slotOff =
      (((size_t)bh * 64 + kb_g) * 64 + lslot) * 8 + (kcol & 7);
  const float bias0 = b_h[kcol], bias1 = b_h[kcol + 1];

  // this wave's 32 producer wave-flags: 4 wgs (k in [ki*128, ki*128+128))
  // x 8 waves; lane<32 watches one each
  const int pflag =
      ((bh * 32 + ki * 4 + (lane >> 3)) * 8 + (lane & 7)) * 4;

  // prefetch step-0 token + embedding pair
  int tok_n = x[em * Sz];
  float2 xv_n = *(const float2*)&W_xh[(size_t)tok_n * Hz + kcol];

  int rp = 0;                               // read generation = s % 3
  for (int s = 0; s < Sz; ++s) {
    const int wp = (rp == 2) ? 0 : rp + 1;  // write generation
    const unsigned tgt = (unsigned)(s + 1); // producers' step-s data flag

    // fine-grained parallel WAIT on 32 producer WAVES (union certifies data)
    {
      for (int it = 0; it < 65536; ++it) {
        unsigned v = 0xFFFFFFFFu;
        if (lane < 32)
          v = __hip_atomic_load(&flags[pflag], __ATOMIC_RELAXED,
                                __HIP_MEMORY_SCOPE_AGENT);
        if (__all(v >= tgt)) break;
        __builtin_amdgcn_s_sleep(1);
      }
      asm volatile("" ::: "memory");
    }

    // issue all 8 A-fragment loads (no drain), consume pairwise with
    // descending vmcnt gates; stale stores only make gates more conservative.
    u32x4 t[8];
    load8_nodrain(&g_hfrag[rp][bh][ki * 8][lane][0], t);
    f32x16 acc0 = {}, acc1 = {};

#define STAGE(J, CNT)                                                          \
    {                                                                          \
      asm volatile("s_waitcnt vmcnt(" #CNT ")"                                 \
                   : "+v"(t[2 * (J)]), "+v"(t[2 * (J) + 1]));                  \
      const int kbp = ki * 8 + 2 * (J);                                        \
      short8 ba = *(const short8*)&ldsW[(size_t)(kbp * 64 + lane) * 8];        \
      short8 bb = *(const short8*)&ldsW[(size_t)((kbp + 1) * 64 + lane) * 8];  \
      acc0 = __builtin_amdgcn_mfma_f32_32x32x16_bf16(*(short8*)&t[2 * (J)],    \
                                                     ba, acc0, 0, 0, 0);       \
      acc1 = __builtin_amdgcn_mfma_f32_32x32x16_bf16(*(short8*)&t[2 * (J) + 1],\
                                                     bb, acc1, 0, 0, 0);       \
    }
    STAGE(0, 6) STAGE(1, 4) STAGE(2, 2) STAGE(3, 0)
#undef STAGE

    // prefetch NEXT step's token + embedding pair (hides gather latency)
    float2 xv = xv_n;
    if (s + 1 < Sz) {
      int t2 = x[em * Sz + s + 1];
      xv_n = *(const float2*)&W_xh[(size_t)t2 * Hz + kcol];
    }

    __syncthreads();     // BAR-A: prev step's epilogue done reading red
    // C/D: col=lane&31, row=(reg&3)+8*(reg>>2)+4*(lane>>5)  [m74/m101]
    {
#pragma unroll
      for (int r = 0; r < 16; ++r) {
        int m = 4 * (lane >> 5) + (r & 3) + 8 * (r >> 2);
        red[ki * 1024 + m * 32 + (bn ^ m)] = acc0[r] + acc1[r];
      }
    }
    __syncthreads();     // BAR-B: all 8 partials in red

    // epilogue: z = sum of 8 partials + emb + bias; h = tanh(z)
    float z0, z1;
    {
      const int o0 = er * 32 + (c0 ^ er);
      const int o1 = er * 32 + ((c0 + 1) ^ er);
      z0 = ((red[o0] + red[1024 + o0]) + (red[2048 + o0] + red[3072 + o0])) +
           ((red[4096 + o0] + red[5120 + o0]) + (red[6144 + o0] + red[7168 + o0]));
      z1 = ((red[o1] + red[1024 + o1]) + (red[2048 + o1] + red[3072 + o1])) +
           ((red[4096 + o1] + red[5120 + o1]) + (red[6144 + o1] + red[7168 + o1]));
    }
    z0 = fast_tanh(z0 + xv.x + bias0);
    z1 = fast_tanh(z1 + xv.y + bias1);

    unsigned w2 = (unsigned)f2bf(z0) | ((unsigned)f2bf(z1) << 16);

    // h store (write-through to L3), per-wave drain, per-wave flag publish
    store4_sc1(&((unsigned short*)g_hfrag)[(size_t)wp * 65536 + slotOff], w2);
    asm volatile("s_waitcnt vmcnt(0)" ::: "memory");   // own stores visible
    if (lane == 0)
      __hip_atomic_store(&flags[(g * 8 + ki) * 4], (unsigned)(s + 2),
                         __ATOMIC_RELAXED, __HIP_MEMORY_SCOPE_AGENT);

    // off the publish path:
    *(unsigned*)&g_hidden[(size_t)s * 65536 + slotOff] = w2;
    if (s == Sz - 1) {
      float* hf = out + (size_t)Bz * Sz * Vz + (size_t)em * Hz + kcol;
      hf[0] = z0; hf[1] = z1;
    }
    rp = wp;
  }
}

// ---------------- Phase 2: logits = hidden @ W_out + b_out -------------------
// grid: 1024 blocks = (s, mi); 4 waves; wave nt computes 32 rows x 32 cols, K=1024
__global__ __launch_bounds__(256) void logits_gemm(
    const float* __restrict__ b_out, float* __restrict__ out)
{
  const int tid = threadIdx.x, lane = tid & 63, nt = tid >> 6;
  const int s = blockIdx.x >> 1, mi = blockIdx.x & 1;
  const unsigned short* ab = &g_hidden[((size_t)s * 8192 + (size_t)mi * 4096) * 8];

  f32x16 acc = {};
#pragma unroll 8
  for (int kb = 0; kb < 64; ++kb) {
    short8 a = *(const short8*)&ab[(size_t)(kb * 64 + lane) * 8];
    short8 b = *(const short8*)&g_wout[(size_t)((kb * 4 + nt) * 64 + lane) * 8];
    acc = __builtin_amdgcn_mfma_f32_32x32x16_bf16(a, b, acc, 0, 0, 0);
  }
  const int col = nt * 32 + (lane & 31);
  const float bo = b_out[col];
  const int rbase = 4 * (lane >> 5);
#pragma unroll
  for (int r = 0; r < 16; ++r) {
    int m = rbase + (r & 3) + 8 * (r >> 2);
    int em = mi * 32 + m;
    out[((size_t)em * Sz + s) * Vz + col] = acc[r] + bo;
  }
}

// ---------------- host launcher ----------------------------------------------
extern "C" void kernel_launch(void* const* d_in, const int* in_sizes, int n_in,
                              void* d_out, int out_size, void* d_ws, size_t ws_size,
                              hipStream_t stream) {
  const int*   x     = (const int*)d_in[0];
  const float* h0    = (const float*)d_in[1];
  const float* W_xh  = (const float*)d_in[2];
  const float* W_hh  = (const float*)d_in[3];
  const float* b_h   = (const float*)d_in[4];
  const float* W_out = (const float*)d_in[5];
  const float* b_out = (const float*)d_in[6];
  float* out = (float*)d_out;

  (void)hipMemsetAsync(d_ws, 0, 8192, stream);    // 512 wave-flag slots (16 B)
  pack_wout<<<64, 256, 0, stream>>>(W_out);
  rnn_persistent<<<NWG, WGT, 0, stream>>>(x, h0, W_xh, W_hh, b_h, out,
                                          (unsigned*)d_ws);
  logits_gemm<<<Sz * 2, 256, 0, stream>>>(b_out, out);
}